// Round 17
// baseline (32879.453 us; speedup 1.0000x reference)
//
#include <hip/hip_runtime.h>
#include <hip/hip_bf16.h>

#define B_   64
#define T_   2048
#define F_   256
#define H_   512
#define GB   4                    // batch groups (16 rows each), 4 independent chains
#define NWG  16                   // 16 WGs; each interleaves 2 chains
#define PAYD 4096                 // payload dwords per group: 16 rows * 256 pairs

typedef __attribute__((ext_vector_type(8))) short bfrag;   // 8 bf16 (MFMA A/B)
typedef __attribute__((ext_vector_type(4))) int   int4v;
typedef __attribute__((ext_vector_type(4))) float f32x4;
typedef __attribute__((ext_vector_type(4))) float float4_t;

__device__ __forceinline__ float fsig(float x)  { return 1.0f / (1.0f + __expf(-x)); }
__device__ __forceinline__ float ftanh(float x) { return 2.0f / (1.0f + __expf(-2.0f * x)) - 1.0f; }
__device__ __forceinline__ short f2bf(float f) {
  __hip_bfloat16 h = __float2bfloat16(f);
  return __builtin_bit_cast(short, h);
}

// ---- coherence-point (sc0 sc1: bypass L1+L2, serviced at MALL) ----
__device__ __forceinline__ int gload4_cc(const void* p) {
  int r;
  asm volatile("global_load_dword %0, %1, off sc0 sc1" : "=v"(r) : "v"(p));
  return r;
}
__device__ __forceinline__ void gstore4_cc(void* p, int d) {
  asm volatile("global_store_dword %0, %1, off sc0 sc1" :: "v"(p), "v"(d));
}
__device__ __forceinline__ int gload_flag(const void* p) {
  int r;
  asm volatile("global_load_dword %0, %1, off sc0 sc1\n\ts_waitcnt vmcnt(0)"
               : "=v"(r) : "v"(p) : "memory");
  return r;
}
__device__ __forceinline__ void vm_drain() {
  asm volatile("s_waitcnt vmcnt(0)" ::: "memory");
  __builtin_amdgcn_sched_barrier(0);   // rule #18
}

// ---------------- init: h0 payload into buf0, flags = 0 (R9 verbatim) --------
__global__ void lstm_init(const float* __restrict__ z, int* __restrict__ pay,
                          int* __restrict__ flags) {
  int i = blockIdx.x * blockDim.x + threadIdx.x;     // 0..16383
  if (i < GB * 16) flags[i] = 0;
  int g  = i >> 12;
  int p  = i & 4095;
  int j  = p >> 8;
  int pr = p & 255;
  int row = 16 * g + j;
  int lo = (int)((unsigned)(unsigned short)f2bf(z[(size_t)row * H_ + 2 * pr])
         | ((unsigned)(unsigned short)f2bf(z[(size_t)row * H_ + 2 * pr + 1]) << 16));
  pay[(size_t)g * PAYD + p] = lo;                    // parity-0 buffer
}

// ---------------- persistent LSTM, 2-chain interleave -------------------------
// WG(p,k), p=wg/8, k=wg%8: runs R9's exact step body for chains bA=p and
// bB=p+2 alternately. While chain A's h-visibility (~1.5us MALL) lands, the
// WG computes chain B's step -> transport latency hidden under compute.
// Per-chain protocol identical to R9 (flags/parity proof unchanged; chains
// independent -> no circular wait; strict alternation bounds skew).
__global__ void __launch_bounds__(256, 1)
lstm_persist(const float* __restrict__ x,
             const float* __restrict__ Wih,  const float* __restrict__ Whh,
             const float* __restrict__ bih,  const float* __restrict__ bhh,
             const float* __restrict__ Wlin, const float* __restrict__ blin,
             float* __restrict__ out, int* __restrict__ pay,
             int* __restrict__ flags)
{
  __shared__ char smem[49152];   // [0,16K) h-tile swz | [16K,48K) W_lin slice

  const int wg  = blockIdx.x;    // 0..15
  const int p   = wg >> 3;       // chain pair: bA=p, bB=p+2
  const int k   = wg & 7;
  const int tid = threadIdx.x;
  const int wv  = tid >> 6;
  const int l   = tid & 63;
  const int l16 = l & 15;
  const int qq  = l >> 4;
  const int swz = (l16 & 7) << 4;
  const int m4  = qq << 2;

  // ---- stage W_lin slice (cols 32k..32k+32, K=512) to LDS, swizzled ----
  {
    const int oc = tid >> 3;
    const float* src = Wlin + (size_t)(32 * k + oc) * H_ + (tid & 7) * 64;
    char* dst = smem + 16384 + oc * 1024;
    #pragma unroll
    for (int i = 0; i < 8; ++i) {
      bfrag tmp;
      #pragma unroll
      for (int e = 0; e < 8; ++e) tmp[e] = f2bf(src[i * 8 + e]);
      *(int4v*)(dst + ((((tid & 7) * 128) + i * 16) ^ ((oc & 7) << 4))) =
          __builtin_bit_cast(int4v, tmp);
    }
  }

  // ---- persistent weight fragments (k-slice; shared by both chains) ----
  bfrag WH[4][16]; bfrag WI[4][8]; float bs[4];
  #pragma unroll
  for (int q = 0; q < 4; ++q) {
    const int grow = q * H_ + k * 64 + wv * 16 + l16;
    #pragma unroll
    for (int kt = 0; kt < 16; ++kt) {
      const float* s = Whh + (size_t)grow * H_ + kt * 32 + qq * 8;
      bfrag w;
      #pragma unroll
      for (int e = 0; e < 8; ++e) w[e] = f2bf(s[e]);
      WH[q][kt] = w;
    }
    #pragma unroll
    for (int kt = 0; kt < 8; ++kt) {
      const float* s = Wih + (size_t)grow * F_ + kt * 32 + qq * 8;
      bfrag w;
      #pragma unroll
      for (int e = 0; e < 8; ++e) w[e] = f2bf(s[e]);
      WI[q][kt] = w;
    }
    bs[q] = bih[grow] + bhh[grow];
  }
  const float blc = (wv < 2) ? blin[32 * k + 16 * wv + l16] : 0.f;

  float c4A[4] = {0.f, 0.f, 0.f, 0.f};
  float c4B[4] = {0.f, 0.f, 0.f, 0.f};
  __syncthreads();

  // ---- R9 step body, parameterized by chain (b, c4) ----
  auto body = [&](int b, float (&c4)[4], int t) {
    f32x4 acc[4] = {{0,0,0,0},{0,0,0,0},{0,0,0,0},{0,0,0,0}};
    {
      const float* xr = x + ((size_t)(16 * b + l16) * T_ + t) * F_ + qq * 8;
      #pragma unroll
      for (int kt = 0; kt < 8; ++kt) {
        float4_t xa = *(const float4_t*)(xr + kt * 32);
        float4_t xb = *(const float4_t*)(xr + kt * 32 + 4);
        bfrag a;
        #pragma unroll
        for (int e = 0; e < 4; ++e) { a[e] = f2bf(xa[e]); a[4 + e] = f2bf(xb[e]); }
        #pragma unroll
        for (int q = 0; q < 4; ++q)
          acc[q] = __builtin_amdgcn_mfma_f32_16x16x32_bf16(a, WI[q][kt], acc[q], 0, 0, 0);
      }
    }

    if (t > 0) {
      const int* myflags = flags + b * 16;
      while (true) {
        int v = gload_flag(&myflags[l & 7]);
        if (__all(v >= t)) break;
        __builtin_amdgcn_s_sleep(1);
      }
      __builtin_amdgcn_sched_barrier(0);
    }
    const int* pp = pay + (size_t)((t & 1) * GB + b) * PAYD + tid;
    int pv[16];
    #pragma unroll
    for (int j = 0; j < 16; ++j) pv[j] = gload4_cc(pp + j * 256);
    vm_drain();
    __syncthreads();           // prior phase's LDS readers done

    #pragma unroll
    for (int j = 0; j < 16; ++j)
      *(int*)(smem + j * 1024 + ((tid * 4) ^ ((j & 7) << 4))) = pv[j];
    __syncthreads();

    f32x4 oacc = {blc, blc, blc, blc};
    #pragma unroll
    for (int kt = 0; kt < 16; ++kt) {
      bfrag a = *(const bfrag*)(smem + l16 * 1024 + ((kt * 64 + qq * 16) ^ swz));
      #pragma unroll
      for (int q = 0; q < 4; ++q)
        acc[q] = __builtin_amdgcn_mfma_f32_16x16x32_bf16(a, WH[q][kt], acc[q], 0, 0, 0);
      if (wv < 2) {
        bfrag wl = *(const bfrag*)(smem + 16384 + (16 * wv + l16) * 1024 +
                                   ((kt * 64 + qq * 16) ^ swz));
        oacc = __builtin_amdgcn_mfma_f32_16x16x32_bf16(a, wl, oacc, 0, 0, 0);
      }
    }

    int* ps = pay + (size_t)(((t + 1) & 1) * GB + b) * PAYD;
    #pragma unroll
    for (int r = 0; r < 4; ++r) {
      float iv = fsig(acc[0][r] + bs[0]);
      float fv = fsig(acc[1][r] + bs[1]);
      float gv = ftanh(acc[2][r] + bs[2]);
      float ov = fsig(acc[3][r] + bs[3]);
      float cn = fv * c4[r] + iv * gv;
      c4[r] = cn;
      float hn = ov * ftanh(cn);
      int hb = (int)(unsigned short)f2bf(hn);
      int pu = __shfl_xor(hb, 1);
      if ((l16 & 1) == 0) {
        int packed = (hb & 0xffff) | (pu << 16);
        gstore4_cc(ps + (m4 + r) * 256 + (32 * k + 8 * wv + (l16 >> 1)), packed);
      }
    }
    vm_drain();
    __syncthreads();
    if (tid == 0)
      gstore4_cc((void*)&flags[b * 16 + k], t + 1);

    if (t > 0 && wv < 2) {
      #pragma unroll
      for (int r = 0; r < 4; ++r)
        out[(size_t)(16 * b + m4 + r) * T_ * F_ + (size_t)(t - 1) * F_ +
            32 * k + 16 * wv + l16] = oacc[r];
    }
  };

  // ---- interleaved chains: B-phase hides A's visibility latency & v.v. ----
  for (int t = 0; t < T_; ++t) {
    body(p,     c4A, t);
    body(p + 2, c4B, t);
  }

  // ---- tails: out[T-1] from h_T for both chains ----
  auto tail = [&](int b) {
    const int* myflags = flags + b * 16;
    while (true) {
      int v = gload_flag(&myflags[l & 7]);
      if (__all(v >= T_)) break;
      __builtin_amdgcn_s_sleep(1);
    }
    __builtin_amdgcn_sched_barrier(0);

    const int* pp = pay + (size_t)((T_ & 1) * GB + b) * PAYD + tid;
    int pv[16];
    #pragma unroll
    for (int j = 0; j < 16; ++j) pv[j] = gload4_cc(pp + j * 256);
    vm_drain();
    __syncthreads();
    #pragma unroll
    for (int j = 0; j < 16; ++j)
      *(int*)(smem + j * 1024 + ((tid * 4) ^ ((j & 7) << 4))) = pv[j];
    __syncthreads();

    if (wv < 2) {
      f32x4 oacc = {blc, blc, blc, blc};
      #pragma unroll
      for (int kt = 0; kt < 16; ++kt) {
        bfrag a  = *(const bfrag*)(smem + l16 * 1024 + ((kt * 64 + qq * 16) ^ swz));
        bfrag wl = *(const bfrag*)(smem + 16384 + (16 * wv + l16) * 1024 +
                                   ((kt * 64 + qq * 16) ^ swz));
        oacc = __builtin_amdgcn_mfma_f32_16x16x32_bf16(a, wl, oacc, 0, 0, 0);
      }
      #pragma unroll
      for (int r = 0; r < 4; ++r)
        out[(size_t)(16 * b + m4 + r) * T_ * F_ + (size_t)(T_ - 1) * F_ +
            32 * k + 16 * wv + l16] = oacc[r];
    }
    __syncthreads();
  };
  tail(p);
  tail(p + 2);
}

extern "C" void kernel_launch(void* const* d_in, const int* in_sizes, int n_in,
                              void* d_out, int out_size, void* d_ws, size_t ws_size,
                              hipStream_t stream) {
  const float* z    = (const float*)d_in[0];
  const float* x    = (const float*)d_in[1];
  const float* Wih  = (const float*)d_in[2];
  const float* Whh  = (const float*)d_in[3];
  const float* bih  = (const float*)d_in[4];
  const float* bhh  = (const float*)d_in[5];
  const float* Wlin = (const float*)d_in[6];
  const float* blin = (const float*)d_in[7];
  float* out = (float*)d_out;

  int* pay   = (int*)d_ws;                              // [0, 128K)
  int* flags = (int*)((char*)d_ws + 192 * 1024);        // [192K, +256B)

  lstm_init<<<64, 256, 0, stream>>>(z, pay, flags);
  lstm_persist<<<NWG, 256, 0, stream>>>(x, Wih, Whh, bih, bhh, Wlin, blin, out,
                                        pay, flags);
}